// Round 1
// baseline (497.017 us; speedup 1.0000x reference)
//
#include <hip/hip_runtime.h>

#define IMG 224
#define HW (IMG * IMG)
#define NB 128
#define NPTS 16384

// ws layout (floats):
//   [0, NB*HW)                  per-batch image accumulator
//   [NB*HW, NB*HW + NB*12)      per-batch params: R[9], zmin, inv_scale, pad
#define IMG_FLOATS ((size_t)NB * HW)
#define PARAMS_OFF IMG_FLOATS
#define PARAMS_STRIDE 12

// ---------------------------------------------------------------------------
// Kernel 1: one block per batch. Compute rotation matrix, z min/max over all
// N points, store params.
// ---------------------------------------------------------------------------
__global__ __launch_bounds__(256) void k_minmax(const float* __restrict__ pts,
                                                const float* __restrict__ az,
                                                const float* __restrict__ el,
                                                float* __restrict__ params) {
    const int b = blockIdx.x;
    const int tid = threadIdx.x;

    float sa, ca, se, ce;
    __sincosf(az[b], &sa, &ca);
    __sincosf(el[b], &se, &ce);
    // R = R_el @ R_az
    const float r00 = ca,       r01 = 0.f, r02 = sa;
    const float r10 = se * sa,  r11 = ce,  r12 = -se * ca;
    const float r20 = -ce * sa, r21 = se,  r22 = ce * ca;

    const float* __restrict__ pb = pts + (size_t)b * NPTS * 3;

    float zmin = 1e30f, zmax = -1e30f;
    for (int n = tid; n < NPTS; n += 256) {
        const float x = pb[n * 3 + 0];
        const float y = pb[n * 3 + 1];
        const float z = pb[n * 3 + 2];
        const float rz = r20 * x + r21 * y + r22 * z;
        zmin = fminf(zmin, rz);
        zmax = fmaxf(zmax, rz);
    }

    __shared__ float smin[256], smax[256];
    smin[tid] = zmin;
    smax[tid] = zmax;
    __syncthreads();
    for (int s = 128; s > 0; s >>= 1) {
        if (tid < s) {
            smin[tid] = fminf(smin[tid], smin[tid + s]);
            smax[tid] = fmaxf(smax[tid], smax[tid + s]);
        }
        __syncthreads();
    }

    if (tid == 0) {
        float* P = params + (size_t)b * PARAMS_STRIDE;
        P[0] = r00; P[1] = r01; P[2] = r02;
        P[3] = r10; P[4] = r11; P[5] = r12;
        P[6] = r20; P[7] = r21; P[8] = r22;
        P[9] = smin[0];
        P[10] = 0.7f / (smax[0] - smin[0] + 1e-6f);
    }
}

// ---------------------------------------------------------------------------
// Kernel 2: splat. 8 blocks per batch, 256 threads, 8 points per thread.
// ---------------------------------------------------------------------------
__global__ __launch_bounds__(256) void k_splat(const float* __restrict__ pts,
                                               const float* __restrict__ params,
                                               float* __restrict__ img) {
    const int b = blockIdx.x >> 3;       // 8 blocks per batch
    const int chunk = blockIdx.x & 7;

    const float* __restrict__ P = params + (size_t)b * PARAMS_STRIDE;
    const float r00 = P[0], r01 = P[1], r02 = P[2];
    const float r10 = P[3], r11 = P[4], r12 = P[5];
    const float r20 = P[6], r21 = P[7], r22 = P[8];
    const float zmin = P[9], inv = P[10];

    const float* __restrict__ pb = pts + (size_t)b * NPTS * 3;
    float* __restrict__ im = img + (size_t)b * HW;

    const int n0 = chunk * 2048 + threadIdx.x;
#pragma unroll
    for (int k = 0; k < 8; ++k) {
        const int n = n0 + k * 256;
        const float x = pb[n * 3 + 0];
        const float y = pb[n * 3 + 1];
        const float z = pb[n * 3 + 2];

        const float rx = r00 * x + r01 * y + r02 * z;
        const float ry = r10 * x + r11 * y + r12 * z;
        const float rz = r20 * x + r21 * y + r22 * z;

        const float feat = 0.3f + (rz - zmin) * inv;

        const float px = (rx + 1.0f) * (0.5f * IMG) - 0.5f;
        const float py = (ry + 1.0f) * (0.5f * IMG) - 0.5f;
        const float px1 = floorf(px);
        const float py1 = floorf(py);
        const float px2 = px1 + 1.0f;
        const float py2 = py1 + 1.0f;

        // mask: px1>=0 && py1>=0 && px2<W && py2<H
        if (px1 >= 0.0f && py1 >= 0.0f && px2 < (float)IMG && py2 < (float)IMG) {
            const float wx2 = px - px1;   // frac x
            const float wx1 = px2 - px;   // 1 - frac x (as computed by ref)
            const float wy2 = py - py1;
            const float wy1 = py2 - py;

            const int ix = (int)px1;
            const int iy = (int)py1;
            float* row1 = im + iy * IMG + ix;
            float* row2 = row1 + IMG;

            atomicAdd(row1,     wx1 * wy1 * feat);  // (py1, px1)
            atomicAdd(row2,     wx1 * wy2 * feat);  // (py2, px1)
            atomicAdd(row1 + 1, wx2 * wy1 * feat);  // (py1, px2)
            atomicAdd(row2 + 1, wx2 * wy2 * feat);  // (py2, px2)
        }
    }
}

// ---------------------------------------------------------------------------
// Kernel 3: broadcast image accumulator to 3 output channels (float4).
// ---------------------------------------------------------------------------
__global__ __launch_bounds__(256) void k_bcast(const float4* __restrict__ img,
                                               float4* __restrict__ out) {
    const int idx = blockIdx.x * 256 + threadIdx.x;
    const int HW4 = HW / 4;                 // 12544
    if (idx >= NB * HW4) return;
    const int b = idx / HW4;
    const int r = idx - b * HW4;
    const float4 v = img[idx];
    float4* o = out + (size_t)b * 3 * HW4 + r;
    o[0] = v;
    o[HW4] = v;
    o[2 * HW4] = v;
}

extern "C" void kernel_launch(void* const* d_in, const int* in_sizes, int n_in,
                              void* d_out, int out_size, void* d_ws, size_t ws_size,
                              hipStream_t stream) {
    const float* pts = (const float*)d_in[0];
    const float* az  = (const float*)d_in[1];
    const float* el  = (const float*)d_in[2];
    float* ws  = (float*)d_ws;
    float* img = ws;                       // NB*HW accumulator
    float* params = ws + PARAMS_OFF;       // NB*12 params
    float* out = (float*)d_out;

    // zero the accumulator
    hipMemsetAsync(img, 0, IMG_FLOATS * sizeof(float), stream);

    k_minmax<<<NB, 256, 0, stream>>>(pts, az, el, params);

    k_splat<<<NB * 8, 256, 0, stream>>>(pts, params, img);

    const int HW4 = HW / 4;
    const int nb = (NB * HW4 + 255) / 256;
    k_bcast<<<nb, 256, 0, stream>>>((const float4*)img, (float4*)out);
}

// Round 2
// 143.752 us; speedup vs baseline: 3.4575x; 3.4575x over previous
//
#include <hip/hip_runtime.h>

#define IMG 224
#define HW (IMG * IMG)
#define NB 128
#define NPTS 16384

#define QUARTERS 4
#define RPB (IMG / QUARTERS)        // 56 rows per block
#define TILE_FLOATS (RPB * IMG)     // 12544 floats = 49 KB LDS

#define PARAMS_STRIDE 12

// ---------------------------------------------------------------------------
// Kernel 1: one block per batch, 1024 threads. Rotation matrix + z min/max.
// ---------------------------------------------------------------------------
__global__ __launch_bounds__(1024) void k_minmax(const float* __restrict__ pts,
                                                 const float* __restrict__ az,
                                                 const float* __restrict__ el,
                                                 float* __restrict__ params) {
    const int b = blockIdx.x;
    const int tid = threadIdx.x;

    float sa, ca, se, ce;
    __sincosf(az[b], &sa, &ca);
    __sincosf(el[b], &se, &ce);
    // R = R_el @ R_az
    const float r20 = -ce * sa, r21 = se, r22 = ce * ca;

    const float* __restrict__ pb = pts + (size_t)b * NPTS * 3;

    float zmin = 1e30f, zmax = -1e30f;
    for (int n = tid; n < NPTS; n += 1024) {
        const float x = pb[n * 3 + 0];
        const float y = pb[n * 3 + 1];
        const float z = pb[n * 3 + 2];
        const float rz = r20 * x + r21 * y + r22 * z;
        zmin = fminf(zmin, rz);
        zmax = fmaxf(zmax, rz);
    }

    __shared__ float smin[1024], smax[1024];
    smin[tid] = zmin;
    smax[tid] = zmax;
    __syncthreads();
    for (int s = 512; s > 0; s >>= 1) {
        if (tid < s) {
            smin[tid] = fminf(smin[tid], smin[tid + s]);
            smax[tid] = fmaxf(smax[tid], smax[tid + s]);
        }
        __syncthreads();
    }

    if (tid == 0) {
        float* P = params + (size_t)b * PARAMS_STRIDE;
        P[0] = ca;       P[1] = 0.f; P[2] = sa;
        P[3] = se * sa;  P[4] = ce;  P[5] = -se * ca;
        P[6] = r20;      P[7] = r21; P[8] = r22;
        P[9] = smin[0];
        P[10] = 0.7f / (smax[0] - smin[0] + 1e-6f);
    }
}

// ---------------------------------------------------------------------------
// Kernel 2: splat with LDS privatization. Grid = NB * QUARTERS blocks.
// Block (b, q) owns image rows [q*RPB, (q+1)*RPB) of batch b, accumulates
// them in LDS via ds_add_f32, then writes its exclusive region directly to
// all 3 output channels (no global accumulator, no atomics to HBM).
// ---------------------------------------------------------------------------
__global__ __launch_bounds__(256) void k_splat(const float* __restrict__ pts,
                                               const float* __restrict__ params,
                                               float* __restrict__ out) {
    const int b = blockIdx.x >> 2;
    const int q = blockIdx.x & 3;
    const int y0 = q * RPB;

    __shared__ float tile[TILE_FLOATS];
    for (int i = threadIdx.x; i < TILE_FLOATS; i += 256) tile[i] = 0.0f;

    const float* __restrict__ P = params + (size_t)b * PARAMS_STRIDE;
    const float r00 = P[0], r02 = P[2];
    const float r10 = P[3], r11 = P[4], r12 = P[5];
    const float r20 = P[6], r21 = P[7], r22 = P[8];
    const float zmin = P[9], inv = P[10];

    const float* __restrict__ pb = pts + (size_t)b * NPTS * 3;
    __syncthreads();

    for (int n = threadIdx.x; n < NPTS; n += 256) {
        const float x = pb[n * 3 + 0];
        const float y = pb[n * 3 + 1];
        const float z = pb[n * 3 + 2];

        const float rx = r00 * x + r02 * z;
        const float ry = r10 * x + r11 * y + r12 * z;
        const float rz = r20 * x + r21 * y + r22 * z;

        const float feat = 0.3f + (rz - zmin) * inv;

        const float px = (rx + 1.0f) * (0.5f * IMG) - 0.5f;
        const float py = (ry + 1.0f) * (0.5f * IMG) - 0.5f;
        const float px1 = floorf(px);
        const float py1 = floorf(py);
        const float px2 = px1 + 1.0f;
        const float py2 = py1 + 1.0f;

        if (px1 >= 0.0f && py1 >= 0.0f && px2 < (float)IMG && py2 < (float)IMG) {
            const float wx2 = px - px1;
            const float wx1 = px2 - px;
            const float wy2 = py - py1;
            const float wy1 = py2 - py;

            const int ix = (int)px1;
            const int iy = (int)py1;
            const int r0 = iy - y0;        // row py1 within this block's tile
            const int r1 = r0 + 1;         // row py2

            if (r0 >= 0 && r0 < RPB) {
                atomicAdd(&tile[r0 * IMG + ix],     wx1 * wy1 * feat);
                atomicAdd(&tile[r0 * IMG + ix + 1], wx2 * wy1 * feat);
            }
            if (r1 >= 0 && r1 < RPB) {
                atomicAdd(&tile[r1 * IMG + ix],     wx1 * wy2 * feat);
                atomicAdd(&tile[r1 * IMG + ix + 1], wx2 * wy2 * feat);
            }
        }
    }

    __syncthreads();

    // Write exclusive region to the 3 broadcast channels.
    const float4* __restrict__ t4 = (const float4*)tile;
    float4* __restrict__ o4 = (float4*)(out + (size_t)b * 3 * HW + (size_t)y0 * IMG);
    const int HW4 = HW / 4;
#pragma unroll
    for (int i = threadIdx.x; i < TILE_FLOATS / 4; i += 256) {
        const float4 v = t4[i];
        o4[i] = v;
        o4[i + HW4] = v;
        o4[i + 2 * HW4] = v;
    }
}

extern "C" void kernel_launch(void* const* d_in, const int* in_sizes, int n_in,
                              void* d_out, int out_size, void* d_ws, size_t ws_size,
                              hipStream_t stream) {
    const float* pts = (const float*)d_in[0];
    const float* az  = (const float*)d_in[1];
    const float* el  = (const float*)d_in[2];
    float* params = (float*)d_ws;
    float* out = (float*)d_out;

    k_minmax<<<NB, 1024, 0, stream>>>(pts, az, el, params);
    k_splat<<<NB * QUARTERS, 256, 0, stream>>>(pts, params, out);
}

// Round 3
// 133.522 us; speedup vs baseline: 3.7224x; 1.0766x over previous
//
#include <hip/hip_runtime.h>

#define IMG 224
#define HW (IMG * IMG)
#define HW4 (HW / 4)
#define NB 128
#define NPTS 16384

#define QUARTERS 4
#define RPB (IMG / QUARTERS)          // 56 rows per block
#define TILE_FLOATS (RPB * IMG)       // 12544 floats = 49 KB LDS
#define THREADS 512

// One fused kernel. Block (b, q) owns image rows [q*RPB, (q+1)*RPB) of
// batch b. It reads all 16K points of batch b twice (pass 1: z min/max,
// pass 2: splat) — the second read is L2-hot, and blocks are indexed so all
// 4 quarter-blocks of a batch share one XCD's L2 (b = blockIdx&127 -> XCD
// b%8 for all quarters). LDS accumulation via ds_add_f32, then the block's
// exclusive region is written directly to the 3 broadcast channels.
__global__ __launch_bounds__(THREADS) void k_render(const float* __restrict__ pts,
                                                    const float* __restrict__ az,
                                                    const float* __restrict__ el,
                                                    float* __restrict__ out) {
    const int b = blockIdx.x & (NB - 1);
    const int q = blockIdx.x >> 7;
    const int y0 = q * RPB;

    __shared__ float tile[TILE_FLOATS];
    __shared__ float wmin[THREADS / 64], wmax[THREADS / 64];

    // Rotation matrix R = R_el @ R_az (wave-uniform scalars).
    float sa, ca, se, ce;
    __sincosf(az[b], &sa, &ca);
    __sincosf(el[b], &se, &ce);
    const float r00 = ca,       r02 = sa;
    const float r10 = se * sa,  r11 = ce,  r12 = -se * ca;
    const float r20 = -ce * sa, r21 = se,  r22 = ce * ca;

    // Zero the LDS tile (visible after the one __syncthreads below).
    for (int i = threadIdx.x; i < TILE_FLOATS; i += THREADS) tile[i] = 0.0f;

    const float4* __restrict__ pb4 = (const float4*)(pts + (size_t)b * NPTS * 3);

    // ---- pass 1: z min/max over all N points (3 float4 = 4 points/iter) ----
    float zmin = 1e30f, zmax = -1e30f;
    for (int it = 0; it < NPTS / (4 * THREADS); ++it) {   // 8 iterations
        const int t = it * THREADS + threadIdx.x;
        const float4 v0 = pb4[3 * t + 0];
        const float4 v1 = pb4[3 * t + 1];
        const float4 v2 = pb4[3 * t + 2];
        float rz;
        rz = r20 * v0.x + r21 * v0.y + r22 * v0.z; zmin = fminf(zmin, rz); zmax = fmaxf(zmax, rz);
        rz = r20 * v0.w + r21 * v1.x + r22 * v1.y; zmin = fminf(zmin, rz); zmax = fmaxf(zmax, rz);
        rz = r20 * v1.z + r21 * v1.w + r22 * v2.x; zmin = fminf(zmin, rz); zmax = fmaxf(zmax, rz);
        rz = r20 * v2.y + r21 * v2.z + r22 * v2.w; zmin = fminf(zmin, rz); zmax = fmaxf(zmax, rz);
    }
    // wave butterfly reduce (64 lanes)
    for (int m = 1; m < 64; m <<= 1) {
        zmin = fminf(zmin, __shfl_xor(zmin, m));
        zmax = fmaxf(zmax, __shfl_xor(zmax, m));
    }
    const int wid = threadIdx.x >> 6;
    if ((threadIdx.x & 63) == 0) { wmin[wid] = zmin; wmax[wid] = zmax; }
    __syncthreads();   // publishes wmin/wmax AND the zeroed tile
    zmin = wmin[0]; zmax = wmax[0];
#pragma unroll
    for (int w = 1; w < THREADS / 64; ++w) {
        zmin = fminf(zmin, wmin[w]);
        zmax = fmaxf(zmax, wmax[w]);
    }
    const float inv = 0.7f / (zmax - zmin + 1e-6f);

    // ---- pass 2: splat (points now L2-hot) ----
    auto splat = [&](float x, float y, float z) {
        const float rx = r00 * x + r02 * z;
        const float ry = r10 * x + r11 * y + r12 * z;
        const float rz = r20 * x + r21 * y + r22 * z;
        const float feat = 0.3f + (rz - zmin) * inv;

        const float px = (rx + 1.0f) * (0.5f * IMG) - 0.5f;
        const float py = (ry + 1.0f) * (0.5f * IMG) - 0.5f;
        const float px1 = floorf(px);
        const float py1 = floorf(py);
        // px2<224 && py2<224  <=>  px1<223 && py1<223 (integer-valued floats)
        if (px1 >= 0.0f && py1 >= 0.0f && px1 < (float)(IMG - 1) && py1 < (float)(IMG - 1)) {
            const float wx2 = px - px1;
            const float wx1 = 1.0f - wx2;
            const float wy2 = py - py1;
            const float wy1 = 1.0f - wy2;

            const int ix = (int)px1;
            const int iy = (int)py1;
            const int r0 = iy - y0;
            const int r1 = r0 + 1;
            if (r0 >= 0 && r0 < RPB) {
                atomicAdd(&tile[r0 * IMG + ix],     wx1 * wy1 * feat);
                atomicAdd(&tile[r0 * IMG + ix + 1], wx2 * wy1 * feat);
            }
            if (r1 >= 0 && r1 < RPB) {
                atomicAdd(&tile[r1 * IMG + ix],     wx1 * wy2 * feat);
                atomicAdd(&tile[r1 * IMG + ix + 1], wx2 * wy2 * feat);
            }
        }
    };

    for (int it = 0; it < NPTS / (4 * THREADS); ++it) {   // 8 iterations
        const int t = it * THREADS + threadIdx.x;
        const float4 v0 = pb4[3 * t + 0];
        const float4 v1 = pb4[3 * t + 1];
        const float4 v2 = pb4[3 * t + 2];
        splat(v0.x, v0.y, v0.z);
        splat(v0.w, v1.x, v1.y);
        splat(v1.z, v1.w, v2.x);
        splat(v2.y, v2.z, v2.w);
    }

    __syncthreads();

    // ---- writeout: exclusive region -> 3 broadcast channels (float4) ----
    const float4* __restrict__ t4 = (const float4*)tile;
    float4* __restrict__ o4 = (float4*)(out + (size_t)b * 3 * HW + (size_t)y0 * IMG);
    for (int i = threadIdx.x; i < TILE_FLOATS / 4; i += THREADS) {
        const float4 v = t4[i];
        o4[i] = v;
        o4[i + HW4] = v;
        o4[i + 2 * HW4] = v;
    }
}

extern "C" void kernel_launch(void* const* d_in, const int* in_sizes, int n_in,
                              void* d_out, int out_size, void* d_ws, size_t ws_size,
                              hipStream_t stream) {
    const float* pts = (const float*)d_in[0];
    const float* az  = (const float*)d_in[1];
    const float* el  = (const float*)d_in[2];
    float* out = (float*)d_out;

    k_render<<<NB * QUARTERS, THREADS, 0, stream>>>(pts, az, el, out);
}